// Round 1
// 535.968 us; speedup vs baseline: 1.0415x; 1.0415x over previous
//
#include <hip/hip_runtime.h>

#define LN_EPS 1e-5f

typedef __attribute__((ext_vector_type(8)))  short bf16x8;    // 8 bf16 = 4 VGPRs
typedef __attribute__((ext_vector_type(16))) float floatx16;  // MFMA 32x32 acc

static __device__ __forceinline__ unsigned short f2bf(float x) {
    union { float f; unsigned u; } v; v.f = x;
    unsigned r = v.u + 0x7FFFu + ((v.u >> 16) & 1u);   // round-to-nearest-even
    return (unsigned short)(r >> 16);
}

// ---------------------------------------------------------------------------
// Kernel 1: per-row MLP head: x2 = relu(LN(relu(LN(feat*W1+b1))@W2+b2))
// Now writes the bf16 A-fragment array DIRECTLY (x2 fp32 never materialized).
// A-frag layout (matches k_fused read): uint4 index g = (R*8+s)*64 + lane,
//   lane = (row&31) + 32*hi, holding cols k = s*16 + hi*8 + {0..7}.
// For a (row, j): s=j>>4, hi=(j>>3)&1, jj=j&7.
// ---------------------------------------------------------------------------
__global__ __launch_bounds__(256) void k1_mlp(
    const float* __restrict__ feat,
    const float* __restrict__ W1, const float* __restrict__ b1,
    const float* __restrict__ g1, const float* __restrict__ be1,
    const float* __restrict__ W2, const float* __restrict__ b2,
    const float* __restrict__ g2, const float* __restrict__ be2,
    unsigned short* __restrict__ Abf)
{
    const int ty = threadIdx.x >> 7;
    const int j  = threadIdx.x & 127;
    const int row = blockIdx.x * 2 + ty;

    __shared__ float sx1[2][128];
    __shared__ float sred[2][2][2];

    const float f = feat[row];
    float v = fmaf(f, W1[j], b1[j]);

    float s = v, q = v * v;
    #pragma unroll
    for (int off = 32; off > 0; off >>= 1) {
        s += __shfl_down(s, off);
        q += __shfl_down(q, off);
    }
    const int wir = j >> 6;
    if ((j & 63) == 0) { sred[ty][wir][0] = s; sred[ty][wir][1] = q; }
    __syncthreads();
    float sum = sred[ty][0][0] + sred[ty][1][0];
    float sq  = sred[ty][0][1] + sred[ty][1][1];
    float mu  = sum * (1.0f / 128.0f);
    float var = fmaf(-mu, mu, sq * (1.0f / 128.0f));
    float x1  = fmaf((v - mu) * rsqrtf(var + LN_EPS), g1[j], be1[j]);
    x1 = fmaxf(x1, 0.0f);
    sx1[ty][j] = x1;
    __syncthreads();

    float a = b2[j];
    #pragma unroll 8
    for (int k = 0; k < 128; ++k)
        a = fmaf(sx1[ty][k], W2[k * 128 + j], a);

    s = a; q = a * a;
    #pragma unroll
    for (int off = 32; off > 0; off >>= 1) {
        s += __shfl_down(s, off);
        q += __shfl_down(q, off);
    }
    if ((j & 63) == 0) { sred[ty][wir][0] = s; sred[ty][wir][1] = q; }
    __syncthreads();
    sum = sred[ty][0][0] + sred[ty][1][0];
    sq  = sred[ty][0][1] + sred[ty][1][1];
    mu  = sum * (1.0f / 128.0f);
    var = fmaf(-mu, mu, sq * (1.0f / 128.0f));
    float x2v = fmaf((a - mu) * rsqrtf(var + LN_EPS), g2[j], be2[j]);
    x2v = fmaxf(x2v, 0.0f);

    // direct bf16 A-fragment store
    const int s4 = j >> 4;
    const int hi = (j >> 3) & 1;
    const int jj = j & 7;
    const int g  = ((row >> 5) * 8 + s4) * 64 + (row & 31) + 32 * hi;
    Abf[(size_t)g * 8 + jj] = f2bf(x2v);
}

// ---------------------------------------------------------------------------
// Repack W3 (fp32 [128][5120]) -> B-frag-ordered bf16 (unchanged, verified).
// B[k][n]: n = lane&31, k = (lane>>5)*8 + j.  Flat: ((t*8+s)*64+lane)*8+j.
// ---------------------------------------------------------------------------
__global__ __launch_bounds__(256) void k_repack_w(
    const float* __restrict__ W3, unsigned int* __restrict__ B)
{
    const int g = blockIdx.x * 256 + threadIdx.x;   // 81920
    const int L = g & 63;
    const int s = (g >> 6) & 7;
    const int t = g >> 9;
    const int n  = t * 32 + (L & 31);
    const int kb = s * 16 + (L >> 5) * 8;
    unsigned short o[8];
    #pragma unroll
    for (int j = 0; j < 8; ++j)
        o[j] = f2bf(W3[(size_t)(kb + j) * 5120 + n]);
    uint4 w;
    w.x = o[0] | ((unsigned)o[1] << 16);
    w.y = o[2] | ((unsigned)o[3] << 16);
    w.z = o[4] | ((unsigned)o[5] << 16);
    w.w = o[6] | ((unsigned)o[7] << 16);
    ((uint4*)B)[g] = w;
}

// ---------------------------------------------------------------------------
// Fused GEMM + einsum. Block = 32 rows x 640 cols (= 4 'o' values), 4 waves.
// Wave w owns exactly one o = cb*4+w (5 col-tiles of 32 = 160 cols = i*5+f).
// MFMA (bf16, 32x32x16) -> acc stays on-CU: dumped to LDS (fp32) in 2 phases
// (2 o-slots of 32x160 -> 57 KB static LDS, 2 blocks/CU), then the basis
// contraction out[row, o*5+d, i*5+m] = sum_f Y[row,o,i,f]*B[row,d,m,f]
// runs straight from LDS. Y never touches HBM.
// C layout (verified m74/m101): col=lane&31, row=(reg&3)+8*(reg>>2)+4*(lane>>5).
// ---------------------------------------------------------------------------
__global__ __launch_bounds__(256) void k_fused(
    const unsigned int* __restrict__ Abf, const unsigned int* __restrict__ Bbf,
    const float* __restrict__ b3, const float* __restrict__ basis,
    float* __restrict__ out)
{
    const int tid  = threadIdx.x;
    const int lane = tid & 63;
    const int w    = tid >> 6;
    const int R    = blockIdx.x;            // 32-row block
    const int cb   = blockIdx.y;            // 4-o block
    const int t0   = cb * 20 + w * 5;       // first global col-tile of this wave

    __shared__ float sY[2][32][160];        // two o-slots, fp32 Y tile
    __shared__ float sB[32 * 125];          // basis rows for this row-block

    for (int idx = tid; idx < 32 * 125; idx += 256)
        sB[idx] = basis[(size_t)R * (32 * 125) + idx];

    floatx16 acc[5];
    #pragma unroll
    for (int tt = 0; tt < 5; ++tt) acc[tt] = (floatx16)0.0f;

    const uint4* Ap = (const uint4*)Abf + (size_t)R * 512 + lane;
    const uint4* Bp = (const uint4*)Bbf + (size_t)t0 * 512 + lane;

    #pragma unroll
    for (int s = 0; s < 8; ++s) {
        bf16x8 a = *(const bf16x8*)(Ap + s * 64);
        #pragma unroll
        for (int tt = 0; tt < 5; ++tt) {
            bf16x8 b = *(const bf16x8*)(Bp + (size_t)tt * 512 + s * 64);
            acc[tt] = __builtin_amdgcn_mfma_f32_32x32x16_bf16(a, b, acc[tt], 0, 0, 0);
        }
    }

    const int m_hi = 4 * (lane >> 5);
    const int nl   = lane & 31;
    float bias[5];
    #pragma unroll
    for (int tt = 0; tt < 5; ++tt) bias[tt] = b3[(t0 + tt) * 32 + nl];

    // einsum thread mapping: 128 threads per o-slot; 2 rows x 4 i each.
    const int l128 = tid & 127;
    const int oh   = tid >> 7;              // which o-slot this thread reads
    const int r0   = (l128 >> 3) * 2;       // 2 consecutive rows
    const int i0   = (l128 & 7) * 4;        // 4 consecutive i

    #pragma unroll
    for (int ph = 0; ph < 2; ++ph) {
        // waves {2ph, 2ph+1} dump their acc into sY slots {0,1}
        if ((w >> 1) == ph) {
            #pragma unroll
            for (int tt = 0; tt < 5; ++tt) {
                #pragma unroll
                for (int reg = 0; reg < 16; ++reg) {
                    const int m = (reg & 3) + 8 * (reg >> 2) + m_hi;
                    sY[w & 1][m][tt * 32 + nl] = acc[tt][reg] + bias[tt];
                }
            }
        }
        __syncthreads();

        const int o = cb * 4 + ph * 2 + oh;
        #pragma unroll
        for (int rr = 0; rr < 2; ++rr) {
            const int row = r0 + rr;
            const float4* yp = (const float4*)(&sY[oh][row][i0 * 5]);
            float4 q0 = yp[0], q1 = yp[1], q2 = yp[2], q3 = yp[3], q4 = yp[4];
            float y[20];
            y[0]=q0.x;  y[1]=q0.y;  y[2]=q0.z;  y[3]=q0.w;
            y[4]=q1.x;  y[5]=q1.y;  y[6]=q1.z;  y[7]=q1.w;
            y[8]=q2.x;  y[9]=q2.y;  y[10]=q2.z; y[11]=q2.w;
            y[12]=q3.x; y[13]=q3.y; y[14]=q3.z; y[15]=q3.w;
            y[16]=q4.x; y[17]=q4.y; y[18]=q4.z; y[19]=q4.w;

            const float* Br = sB + row * 125;
            float* orow = out + (size_t)(R * 32 + row) * 25600
                              + (size_t)o * 800 + i0 * 5;
            #pragma unroll
            for (int d = 0; d < 5; ++d) {
                float Bv[25];
                #pragma unroll
                for (int qq = 0; qq < 25; ++qq) Bv[qq] = Br[d * 25 + qq];
                float vv[20];
                #pragma unroll
                for (int p = 0; p < 4; ++p) {
                    #pragma unroll
                    for (int m = 0; m < 5; ++m) {
                        float t = y[p * 5 + 0] * Bv[m * 5 + 0];
                        t = fmaf(y[p * 5 + 1], Bv[m * 5 + 1], t);
                        t = fmaf(y[p * 5 + 2], Bv[m * 5 + 2], t);
                        t = fmaf(y[p * 5 + 3], Bv[m * 5 + 3], t);
                        t = fmaf(y[p * 5 + 4], Bv[m * 5 + 4], t);
                        vv[p * 5 + m] = t;
                    }
                }
                float4* dst = (float4*)(orow + d * 160);
                dst[0] = make_float4(vv[0],  vv[1],  vv[2],  vv[3]);
                dst[1] = make_float4(vv[4],  vv[5],  vv[6],  vv[7]);
                dst[2] = make_float4(vv[8],  vv[9],  vv[10], vv[11]);
                dst[3] = make_float4(vv[12], vv[13], vv[14], vv[15]);
                dst[4] = make_float4(vv[16], vv[17], vv[18], vv[19]);
            }
        }
        __syncthreads();   // readers done before next phase overwrites sY
    }
}

// ---------------------------------------------------------------------------
extern "C" void kernel_launch(void* const* d_in, const int* in_sizes, int n_in,
                              void* d_out, int out_size, void* d_ws, size_t ws_size,
                              hipStream_t stream)
{
    const float* feat  = (const float*)d_in[0];
    const float* basis = (const float*)d_in[1];
    const float* W1    = (const float*)d_in[2];
    const float* b1    = (const float*)d_in[3];
    const float* g1    = (const float*)d_in[4];
    const float* be1   = (const float*)d_in[5];
    const float* W2    = (const float*)d_in[6];
    const float* b2    = (const float*)d_in[7];
    const float* g2    = (const float*)d_in[8];
    const float* be2   = (const float*)d_in[9];
    const float* W3    = (const float*)d_in[10];
    const float* b3    = (const float*)d_in[11];

    float* out = (float*)d_out;

    // ws layout (bytes): Abf [0, 1M) | Bbf [1M, 2.25M)   (no Y, no x2)
    char* ws = (char*)d_ws;
    unsigned short* Abf = (unsigned short*)(ws);              // 65536*16 B  = 1,048,576
    unsigned int*   Bbf = (unsigned int*)(ws + 1048576);      // 81920*16 B  = 1,310,720

    const int rows = 4096;   // b*n*h = 2*64*32

    k1_mlp<<<rows / 2, 256, 0, stream>>>(feat, W1, b1, g1, be1, W2, b2, g2, be2, Abf);
    k_repack_w<<<320, 256, 0, stream>>>(W3, (unsigned int*)Bbf);

    dim3 fgrid(rows / 32, 8);
    k_fused<<<fgrid, 256, 0, stream>>>((const unsigned int*)Abf, Bbf, b3, basis, out);
}